// Round 1
// baseline (88.459 us; speedup 1.0000x reference)
//
#include <hip/hip_runtime.h>
#include <hip/hip_bf16.h>

#define B_DIM 16
#define T_DIM 2048
#define NI 128
#define NO 64
#define TCHUNK 64
#define NCHUNK (T_DIM / TCHUNK)   // 32 chunks -> 512 blocks

typedef __attribute__((ext_vector_type(8))) short short8;
typedef __attribute__((ext_vector_type(4))) float floatx4;

__device__ __forceinline__ unsigned short f2bf(float f) {
    union { float f; unsigned int u; } v; v.f = f;
    unsigned int u = v.u;
    return (unsigned short)((u + 0x7FFFu + ((u >> 16) & 1u)) >> 16);  // RNE
}

// Main fused kernel: distances -> softmax -> W^T X accumulation.
// grid = B_DIM * NCHUNK blocks of 256 threads. 2 blocks/CU (58KB LDS).
__global__ __launch_bounds__(256) void lde_main(
    const float* __restrict__ x,   // (B,T,NI)
    const float* __restrict__ s,   // (NO)
    const float* __restrict__ m,   // (NI,NO)
    float* __restrict__ wx_acc,    // (B,NO,NI) = d_out, pre-zeroed, atomically accumulated
    float* __restrict__ w1_acc)    // (B,NO) in ws, pre-zeroed
{
    // All MFMA operands stored in exact fragment order: [tile][kstep][lane][j]
    // so every ds_read_b128 is lane-sequential (conflict-free).
    __shared__ unsigned short x_frag [4 * 4 * 64 * 8]; // A of GEMM1: x[t][i], 16KB
    __shared__ unsigned short xT_frag[8 * 2 * 64 * 8]; // B of GEMM2: x[t][i] keyed by i, 16KB
    __shared__ unsigned short m_frag [4 * 4 * 64 * 8]; // B of GEMM1: m[i][o] keyed by o, 16KB
    __shared__ unsigned short wT_frag[4 * 2 * 64 * 8]; // A of GEMM2: w[t][o] keyed by o, 8KB
    __shared__ float xx2[256];   // per-thread partial sum of squares of x rows
    __shared__ float xxc[TCHUNK];
    __shared__ float mm_s[NO];
    __shared__ float ss_s[NO];
    __shared__ float w1_s[NO];

    const int tid   = threadIdx.x;
    const int b     = blockIdx.x >> 5;       // / NCHUNK
    const int chunk = blockIdx.x & (NCHUNK - 1);
    const int t0    = chunk * TCHUNK;

    if (tid < NO) { mm_s[tid] = 0.f; w1_s[tid] = 0.f; ss_s[tid] = s[tid]; }
    __syncthreads();

    // ---- stage x chunk: 64 rows x 128 cols. thread = (t = tid>>2, quarter = tid&3)
    {
        const int t  = tid >> 2;
        const int q4 = tid & 3;
        const float* xg = x + ((size_t)b * T_DIM + t0 + t) * NI + q4 * 32;
        const int ttile = t >> 4, tm = t & 15;
        const int ksT = t >> 5, qT = (t & 31) >> 3, jT = t & 7; // xT coords for this t
        float sumsq = 0.f;
        #pragma unroll
        for (int f = 0; f < 8; ++f) {
            float4 v = reinterpret_cast<const float4*>(xg)[f];
            sumsq += v.x * v.x + v.y * v.y + v.z * v.z + v.w * v.w;
            const int i0 = q4 * 32 + f * 4;
            unsigned short h0 = f2bf(v.x), h1 = f2bf(v.y), h2 = f2bf(v.z), h3 = f2bf(v.w);
            // x_frag (A-frag layout): ttile, kstep=i>>5, slot = tm + 16*((i&31)>>3), j=i&7
            {
                const int ks = i0 >> 5, q = (i0 & 31) >> 3, j0 = i0 & 7;
                const int base = (((ttile * 4 + ks) * 64) + tm + 16 * q) * 8 + j0;
                ushort4 hv; hv.x = h0; hv.y = h1; hv.z = h2; hv.w = h3;
                *reinterpret_cast<ushort4*>(&x_frag[base]) = hv;
            }
            // xT_frag (B-frag of GEMM2): itile=i>>4, kstep=t>>5, slot=(i&15)+16*qT, j=jT
            {
                int i;
                i = i0 + 0; xT_frag[(((i >> 4) * 2 + ksT) * 64 + (i & 15) + 16 * qT) * 8 + jT] = h0;
                i = i0 + 1; xT_frag[(((i >> 4) * 2 + ksT) * 64 + (i & 15) + 16 * qT) * 8 + jT] = h1;
                i = i0 + 2; xT_frag[(((i >> 4) * 2 + ksT) * 64 + (i & 15) + 16 * qT) * 8 + jT] = h2;
                i = i0 + 3; xT_frag[(((i >> 4) * 2 + ksT) * 64 + (i & 15) + 16 * qT) * 8 + jT] = h3;
            }
        }
        xx2[tid] = sumsq;
    }

    // ---- stage m: thread = (o = tid&63, iblock = tid>>6). coalesced global reads.
    {
        const int o = tid & 63;
        const int ib = tid >> 6;             // kstep 0..3, i in [32*ib, 32*ib+32)
        const int otile = o >> 4, om = o & 15;
        float mml = 0.f;
        #pragma unroll
        for (int ii = 0; ii < 32; ++ii) {
            const int i = ib * 32 + ii;
            const float v = m[(size_t)i * NO + o];
            mml += v * v;
            const int q = ii >> 3, j = ii & 7;
            m_frag[(((otile * 4 + ib) * 64) + om + 16 * q) * 8 + j] = f2bf(v);
        }
        atomicAdd(&mm_s[o], mml);
    }
    __syncthreads();
    if (tid < TCHUNK)
        xxc[tid] = xx2[4 * tid] + xx2[4 * tid + 1] + xx2[4 * tid + 2] + xx2[4 * tid + 3];
    __syncthreads();

    const int wv   = tid >> 6;   // wave = ttile (GEMM1) = otile (GEMM2)
    const int lane = tid & 63;
    const int quad = lane >> 4, c = lane & 15;

    // ---- GEMM1: S[t][o] = sum_i x[t][i]*m[i][o].  M=t(16/wave), N=o(64), K=128.
    floatx4 zero = {0.f, 0.f, 0.f, 0.f};
    floatx4 acc[4];
    #pragma unroll
    for (int ot = 0; ot < 4; ++ot) acc[ot] = zero;
    #pragma unroll
    for (int ks = 0; ks < 4; ++ks) {
        short8 a = *reinterpret_cast<const short8*>(&x_frag[((wv * 4 + ks) * 64 + lane) * 8]);
        #pragma unroll
        for (int ot = 0; ot < 4; ++ot) {
            short8 bb = *reinterpret_cast<const short8*>(&m_frag[((ot * 4 + ks) * 64 + lane) * 8]);
            acc[ot] = __builtin_amdgcn_mfma_f32_16x16x32_bf16(a, bb, acc[ot], 0, 0, 0);
        }
    }

    // ---- d = s_o*(xx_t - 2 dot + mm_o); softmax over o (regs + shfl within 16-lane group)
    float sv[4], mv[4];
    #pragma unroll
    for (int ot = 0; ot < 4; ++ot) { sv[ot] = ss_s[16 * ot + c]; mv[ot] = mm_s[16 * ot + c]; }
    floatx4 xxq = *reinterpret_cast<const floatx4*>(&xxc[wv * 16 + quad * 4]);

    float w[4][4];
    #pragma unroll
    for (int r = 0; r < 4; ++r) {
        float mx = -1e30f;
        #pragma unroll
        for (int ot = 0; ot < 4; ++ot) {
            float d = sv[ot] * (xxq[r] - 2.f * acc[ot][r] + mv[ot]);
            w[ot][r] = d;
            mx = fmaxf(mx, d);
        }
        #pragma unroll
        for (int off = 1; off < 16; off <<= 1) mx = fmaxf(mx, __shfl_xor(mx, off, 64));
        float sum = 0.f;
        #pragma unroll
        for (int ot = 0; ot < 4; ++ot) { float e = __expf(w[ot][r] - mx); w[ot][r] = e; sum += e; }
        #pragma unroll
        for (int off = 1; off < 16; off <<= 1) sum += __shfl_xor(sum, off, 64);
        const float inv = 1.f / sum;
        #pragma unroll
        for (int ot = 0; ot < 4; ++ot) w[ot][r] *= inv;
    }

    // ---- W1[o] += sum_t w : reduce 4 regs, then quads via shfl, then LDS atomic
    #pragma unroll
    for (int ot = 0; ot < 4; ++ot) {
        float lsum = w[ot][0] + w[ot][1] + w[ot][2] + w[ot][3];
        lsum += __shfl_xor(lsum, 16, 64);
        lsum += __shfl_xor(lsum, 32, 64);
        if (quad == 0) atomicAdd(&w1_s[16 * ot + c], lsum);
    }

    // ---- write w to wT_frag (A-frag layout of GEMM2: A[m=o][k=t])
    #pragma unroll
    for (int ot = 0; ot < 4; ++ot)
        #pragma unroll
        for (int r = 0; r < 4; ++r) {
            const int t  = wv * 16 + quad * 4 + r;
            const int ks = t >> 5, qd = (t & 31) >> 3, j = t & 7;
            wT_frag[((ot * 2 + ks) * 64 + c + 16 * qd) * 8 + j] = f2bf(w[ot][r]);
        }
    __syncthreads();

    // ---- GEMM2: E[o][i] = sum_t w[t][o]*x[t][i].  M=o(16/wave), N=i(128), K=64.
    floatx4 acc2[8];
    #pragma unroll
    for (int it = 0; it < 8; ++it) acc2[it] = zero;
    #pragma unroll
    for (int ks = 0; ks < 2; ++ks) {
        short8 a = *reinterpret_cast<const short8*>(&wT_frag[((wv * 2 + ks) * 64 + lane) * 8]);
        #pragma unroll
        for (int it = 0; it < 8; ++it) {
            short8 bb = *reinterpret_cast<const short8*>(&xT_frag[((it * 2 + ks) * 64 + lane) * 8]);
            acc2[it] = __builtin_amdgcn_mfma_f32_16x16x32_bf16(a, bb, acc2[it], 0, 0, 0);
        }
    }

    // ---- accumulate into global (device-scope atomics, cross-XCD safe)
    float* wxb = wx_acc + (size_t)b * NO * NI;
    const int obase = wv * 16 + quad * 4;
    #pragma unroll
    for (int it = 0; it < 8; ++it) {
        const int i = it * 16 + c;
        #pragma unroll
        for (int r = 0; r < 4; ++r)
            atomicAdd(&wxb[(obase + r) * NI + i], acc2[it][r]);
    }
    if (tid < NO) atomicAdd(&w1_acc[b * NO + tid], w1_s[tid]);
}

// Epilogue: out = (Wx - W1*m^T) / T, in place over d_out.
__global__ __launch_bounds__(256) void lde_final(
    float* __restrict__ out,            // (B,NO,NI), currently holds Wx sums
    const float* __restrict__ w1_acc,   // (B,NO)
    const float* __restrict__ m)        // (NI,NO)
{
    const int idx = blockIdx.x * 256 + threadIdx.x;
    const int i = idx & 127;
    const int o = (idx >> 7) & 63;
    const int b = idx >> 13;
    out[idx] = (out[idx] - w1_acc[b * NO + o] * m[i * NO + o]) * (1.f / (float)T_DIM);
}

extern "C" void kernel_launch(void* const* d_in, const int* in_sizes, int n_in,
                              void* d_out, int out_size, void* d_ws, size_t ws_size,
                              hipStream_t stream) {
    const float* x = (const float*)d_in[0];
    const float* s = (const float*)d_in[1];
    const float* m = (const float*)d_in[2];
    float* out = (float*)d_out;            // B*NO*NI = 131072 floats
    float* w1  = (float*)d_ws;             // B*NO = 1024 floats

    hipMemsetAsync(d_out, 0, (size_t)B_DIM * NO * NI * sizeof(float), stream);
    hipMemsetAsync(d_ws, 0, (size_t)B_DIM * NO * sizeof(float), stream);

    lde_main<<<dim3(B_DIM * NCHUNK), dim3(256), 0, stream>>>(x, s, m, out, w1);
    lde_final<<<dim3((B_DIM * NO * NI) / 256), dim3(256), 0, stream>>>(out, w1, m);
}

// Round 2
// 79.129 us; speedup vs baseline: 1.1179x; 1.1179x over previous
//
#include <hip/hip_runtime.h>
#include <hip/hip_bf16.h>

#define B_DIM 16
#define T_DIM 2048
#define NI 128
#define NO 64
#define TCHUNK 64
#define NCHUNK (T_DIM / TCHUNK)   // 32 chunks -> 512 blocks

typedef __attribute__((ext_vector_type(8))) short short8;
typedef __attribute__((ext_vector_type(4))) float floatx4;

__device__ __forceinline__ unsigned short f2bf(float f) {
    union { float f; unsigned int u; } v; v.f = f;
    unsigned int u = v.u;
    return (unsigned short)((u + 0x7FFFu + ((u >> 16) & 1u)) >> 16);  // RNE
}

// Main fused kernel: distances -> softmax -> W^T X partials (atomic-free).
// grid = B_DIM * NCHUNK = 512 blocks of 256 threads. 2 blocks/CU (58KB LDS).
__global__ __launch_bounds__(256) void lde_main(
    const float* __restrict__ x,   // (B,T,NI)
    const float* __restrict__ s,   // (NO)
    const float* __restrict__ m,   // (NI,NO)
    float* __restrict__ part_e,    // (B*NCHUNK, NO, NI) partials in ws
    float* __restrict__ part_w1)   // (B*NCHUNK, NO) partials in ws
{
    // All MFMA operands stored in exact fragment order: [tile][kstep][lane][j]
    // so every ds_read_b128 is lane-sequential (conflict-free).
    __shared__ unsigned short x_frag [4 * 4 * 64 * 8]; // A of GEMM1: x[t][i], 16KB
    __shared__ unsigned short xT_frag[8 * 2 * 64 * 8]; // B of GEMM2: x[t][i] keyed by i, 16KB
    __shared__ unsigned short m_frag [4 * 4 * 64 * 8]; // B of GEMM1: m[i][o] keyed by o, 16KB
    __shared__ unsigned short wT_frag[4 * 2 * 64 * 8]; // A of GEMM2: w[t][o] keyed by o, 8KB
    __shared__ float xx2[256];   // per-thread partial sum of squares of x rows
    __shared__ float xxc[TCHUNK];
    __shared__ float mm_s[NO];
    __shared__ float ss_s[NO];
    __shared__ float w1_s[NO];

    const int tid   = threadIdx.x;
    const int b     = blockIdx.x >> 5;       // / NCHUNK
    const int chunk = blockIdx.x & (NCHUNK - 1);
    const int t0    = chunk * TCHUNK;

    if (tid < NO) { mm_s[tid] = 0.f; w1_s[tid] = 0.f; ss_s[tid] = s[tid]; }
    __syncthreads();

    // ---- stage x chunk: 64 rows x 128 cols. thread = (t = tid>>2, quarter = tid&3)
    {
        const int t  = tid >> 2;
        const int q4 = tid & 3;
        const float* xg = x + ((size_t)b * T_DIM + t0 + t) * NI + q4 * 32;
        const int ttile = t >> 4, tm = t & 15;
        const int ksT = t >> 5, qT = (t & 31) >> 3, jT = t & 7; // xT coords for this t
        float sumsq = 0.f;
        #pragma unroll
        for (int f = 0; f < 8; ++f) {
            float4 v = reinterpret_cast<const float4*>(xg)[f];
            sumsq += v.x * v.x + v.y * v.y + v.z * v.z + v.w * v.w;
            const int i0 = q4 * 32 + f * 4;
            unsigned short h0 = f2bf(v.x), h1 = f2bf(v.y), h2 = f2bf(v.z), h3 = f2bf(v.w);
            // x_frag (A-frag layout): ttile, kstep=i>>5, slot = tm + 16*((i&31)>>3), j=i&7
            {
                const int ks = i0 >> 5, q = (i0 & 31) >> 3, j0 = i0 & 7;
                const int base = (((ttile * 4 + ks) * 64) + tm + 16 * q) * 8 + j0;
                ushort4 hv; hv.x = h0; hv.y = h1; hv.z = h2; hv.w = h3;
                *reinterpret_cast<ushort4*>(&x_frag[base]) = hv;
            }
            // xT_frag (B-frag of GEMM2): itile=i>>4, kstep=t>>5, slot=(i&15)+16*qT, j=jT
            {
                int i;
                i = i0 + 0; xT_frag[(((i >> 4) * 2 + ksT) * 64 + (i & 15) + 16 * qT) * 8 + jT] = h0;
                i = i0 + 1; xT_frag[(((i >> 4) * 2 + ksT) * 64 + (i & 15) + 16 * qT) * 8 + jT] = h1;
                i = i0 + 2; xT_frag[(((i >> 4) * 2 + ksT) * 64 + (i & 15) + 16 * qT) * 8 + jT] = h2;
                i = i0 + 3; xT_frag[(((i >> 4) * 2 + ksT) * 64 + (i & 15) + 16 * qT) * 8 + jT] = h3;
            }
        }
        xx2[tid] = sumsq;
    }

    // ---- stage m: thread = (o = tid&63, iblock = tid>>6). coalesced global reads.
    {
        const int o = tid & 63;
        const int ib = tid >> 6;             // kstep 0..3, i in [32*ib, 32*ib+32)
        const int otile = o >> 4, om = o & 15;
        float mml = 0.f;
        #pragma unroll
        for (int ii = 0; ii < 32; ++ii) {
            const int i = ib * 32 + ii;
            const float v = m[(size_t)i * NO + o];
            mml += v * v;
            const int q = ii >> 3, j = ii & 7;
            m_frag[(((otile * 4 + ib) * 64) + om + 16 * q) * 8 + j] = f2bf(v);
        }
        atomicAdd(&mm_s[o], mml);
    }
    __syncthreads();
    if (tid < TCHUNK)
        xxc[tid] = xx2[4 * tid] + xx2[4 * tid + 1] + xx2[4 * tid + 2] + xx2[4 * tid + 3];
    __syncthreads();

    const int wv   = tid >> 6;   // wave = ttile (GEMM1) = otile (GEMM2)
    const int lane = tid & 63;
    const int quad = lane >> 4, c = lane & 15;

    // ---- GEMM1: S[t][o] = sum_i x[t][i]*m[i][o].  M=t(16/wave), N=o(64), K=128.
    floatx4 zero = {0.f, 0.f, 0.f, 0.f};
    floatx4 acc[4];
    #pragma unroll
    for (int ot = 0; ot < 4; ++ot) acc[ot] = zero;
    #pragma unroll
    for (int ks = 0; ks < 4; ++ks) {
        short8 a = *reinterpret_cast<const short8*>(&x_frag[((wv * 4 + ks) * 64 + lane) * 8]);
        #pragma unroll
        for (int ot = 0; ot < 4; ++ot) {
            short8 bb = *reinterpret_cast<const short8*>(&m_frag[((ot * 4 + ks) * 64 + lane) * 8]);
            acc[ot] = __builtin_amdgcn_mfma_f32_16x16x32_bf16(a, bb, acc[ot], 0, 0, 0);
        }
    }

    // ---- d = s_o*(xx_t - 2 dot + mm_o); softmax over o (regs + shfl within 16-lane group)
    float sv[4], mv[4];
    #pragma unroll
    for (int ot = 0; ot < 4; ++ot) { sv[ot] = ss_s[16 * ot + c]; mv[ot] = mm_s[16 * ot + c]; }
    floatx4 xxq = *reinterpret_cast<const floatx4*>(&xxc[wv * 16 + quad * 4]);

    float w[4][4];
    #pragma unroll
    for (int r = 0; r < 4; ++r) {
        float mx = -1e30f;
        #pragma unroll
        for (int ot = 0; ot < 4; ++ot) {
            float d = sv[ot] * (xxq[r] - 2.f * acc[ot][r] + mv[ot]);
            w[ot][r] = d;
            mx = fmaxf(mx, d);
        }
        #pragma unroll
        for (int off = 1; off < 16; off <<= 1) mx = fmaxf(mx, __shfl_xor(mx, off, 64));
        float sum = 0.f;
        #pragma unroll
        for (int ot = 0; ot < 4; ++ot) { float e = __expf(w[ot][r] - mx); w[ot][r] = e; sum += e; }
        #pragma unroll
        for (int off = 1; off < 16; off <<= 1) sum += __shfl_xor(sum, off, 64);
        const float inv = 1.f / sum;
        #pragma unroll
        for (int ot = 0; ot < 4; ++ot) w[ot][r] *= inv;
    }

    // ---- W1[o] += sum_t w : reduce 4 regs, then quads via shfl, then LDS atomic
    #pragma unroll
    for (int ot = 0; ot < 4; ++ot) {
        float lsum = w[ot][0] + w[ot][1] + w[ot][2] + w[ot][3];
        lsum += __shfl_xor(lsum, 16, 64);
        lsum += __shfl_xor(lsum, 32, 64);
        if (quad == 0) atomicAdd(&w1_s[16 * ot + c], lsum);
    }

    // ---- write w to wT_frag (A-frag layout of GEMM2: A[m=o][k=t])
    #pragma unroll
    for (int ot = 0; ot < 4; ++ot)
        #pragma unroll
        for (int r = 0; r < 4; ++r) {
            const int t  = wv * 16 + quad * 4 + r;
            const int ks = t >> 5, qd = (t & 31) >> 3, j = t & 7;
            wT_frag[((ot * 2 + ks) * 64 + c + 16 * qd) * 8 + j] = f2bf(w[ot][r]);
        }
    __syncthreads();

    // ---- GEMM2: E[o][i] = sum_t w[t][o]*x[t][i].  M=o(16/wave), N=i(128), K=64.
    floatx4 acc2[8];
    #pragma unroll
    for (int it = 0; it < 8; ++it) acc2[it] = zero;
    #pragma unroll
    for (int ks = 0; ks < 2; ++ks) {
        short8 a = *reinterpret_cast<const short8*>(&wT_frag[((wv * 2 + ks) * 64 + lane) * 8]);
        #pragma unroll
        for (int it = 0; it < 8; ++it) {
            short8 bb = *reinterpret_cast<const short8*>(&xT_frag[((it * 2 + ks) * 64 + lane) * 8]);
            acc2[it] = __builtin_amdgcn_mfma_f32_16x16x32_bf16(a, bb, acc2[it], 0, 0, 0);
        }
    }

    // ---- store per-block partials (atomic-free, coalesced)
    float* pe = part_e + (size_t)blockIdx.x * (NO * NI);
    const int obase = wv * 16 + quad * 4;
    #pragma unroll
    for (int it = 0; it < 8; ++it) {
        const int i = it * 16 + c;
        #pragma unroll
        for (int r = 0; r < 4; ++r)
            pe[(obase + r) * NI + i] = acc2[it][r];
    }
    if (tid < NO) part_w1[blockIdx.x * NO + tid] = w1_s[tid];
}

// Reduce: out[b,o,i] = (sum_c part_e[b,c,o,i] - W1[b,o]*m[i,o]) / T
// grid = B*32 = 512 blocks; block handles 2 o-values x 128 i.
__global__ __launch_bounds__(256) void lde_reduce(
    const float* __restrict__ part_e,   // (B*NCHUNK, NO, NI)
    const float* __restrict__ part_w1,  // (B*NCHUNK, NO)
    const float* __restrict__ m,        // (NI,NO)
    float* __restrict__ out)            // (B,NO,NI)
{
    const int tid = threadIdx.x;
    const int b   = blockIdx.x >> 5;
    const int seg = blockIdx.x & 31;     // which pair of o-rows
    const int o0  = seg * 2;
    const int lo  = tid >> 7;            // 0/1
    const int i   = tid & 127;
    const int o   = o0 + lo;

    // W1[b, o0+{0,1}]: threads 0..63 each read one (chunk, lo) value, shfl-reduce
    __shared__ float w1s[2];
    float w1v = 0.f;
    if (tid < 64)
        w1v = part_w1[((size_t)b * NCHUNK + (tid & 31)) * NO + o0 + (tid >> 5)];
    #pragma unroll
    for (int off = 1; off < 32; off <<= 1) w1v += __shfl_xor(w1v, off, 64);
    if (tid < 64 && (tid & 31) == 0) w1s[tid >> 5] = w1v;
    __syncthreads();

    const float* pe = part_e + (size_t)b * NCHUNK * NO * NI + (size_t)o * NI + i;
    float acc0 = 0.f, acc1 = 0.f, acc2 = 0.f, acc3 = 0.f;
    #pragma unroll
    for (int cc = 0; cc < NCHUNK; cc += 4) {
        acc0 += pe[(size_t)(cc + 0) * NO * NI];
        acc1 += pe[(size_t)(cc + 1) * NO * NI];
        acc2 += pe[(size_t)(cc + 2) * NO * NI];
        acc3 += pe[(size_t)(cc + 3) * NO * NI];
    }
    const float e = (acc0 + acc1) + (acc2 + acc3);
    out[((size_t)b * NO + o) * NI + i] = (e - w1s[lo] * m[i * NO + o]) * (1.f / (float)T_DIM);
}

extern "C" void kernel_launch(void* const* d_in, const int* in_sizes, int n_in,
                              void* d_out, int out_size, void* d_ws, size_t ws_size,
                              hipStream_t stream) {
    const float* x = (const float*)d_in[0];
    const float* s = (const float*)d_in[1];
    const float* m = (const float*)d_in[2];
    float* out = (float*)d_out;                          // B*NO*NI floats
    float* part_e  = (float*)d_ws;                       // 512*8192 floats = 16.8 MB
    float* part_w1 = part_e + (size_t)B_DIM * NCHUNK * NO * NI;  // 512*64 floats

    lde_main<<<dim3(B_DIM * NCHUNK), dim3(256), 0, stream>>>(x, s, m, part_e, part_w1);
    lde_reduce<<<dim3(B_DIM * NCHUNK), dim3(256), 0, stream>>>(part_e, part_w1, m, out);
}

// Round 3
// 76.442 us; speedup vs baseline: 1.1572x; 1.0352x over previous
//
#include <hip/hip_runtime.h>
#include <hip/hip_bf16.h>

#define B_DIM 16
#define T_DIM 2048
#define NI 128
#define NO 64
#define TCHUNK 64
#define NCHUNK (T_DIM / TCHUNK)   // 32 chunks -> 512 blocks

typedef __attribute__((ext_vector_type(8))) short short8;
typedef __attribute__((ext_vector_type(4))) float floatx4;

__device__ __forceinline__ unsigned short f2bf(float f) {
    union { float f; unsigned int u; } v; v.f = f;
    unsigned int u = v.u;
    return (unsigned short)((u + 0x7FFFu + ((u >> 16) & 1u)) >> 16);  // RNE
}
__device__ __forceinline__ float bf2f(unsigned short h) {
    union { unsigned int u; float f; } v; v.u = ((unsigned int)h) << 16; return v.f;
}

// Main fused kernel: distances -> softmax -> E^T partials (bf16, lane-sequential).
// grid = B_DIM * NCHUNK = 512 blocks of 256 threads. 2 blocks/CU (56KB LDS).
__global__ __launch_bounds__(256) void lde_main(
    const float* __restrict__ x,          // (B,T,NI)
    const float* __restrict__ s,          // (NO)
    const float* __restrict__ m,          // (NI,NO)
    unsigned short* __restrict__ part_e,  // (B*NCHUNK, 8192) bf16, lane-sequential order
    float* __restrict__ part_w1)          // (B*NCHUNK, NO)
{
    // All MFMA operands stored in exact fragment order: [tile][kstep][lane][j]
    // so every ds_read_b128 is lane-sequential (conflict-free).
    __shared__ unsigned short x_frag [4 * 4 * 64 * 8]; // A of GEMM1: x[t][i], 16KB
    __shared__ unsigned short xT_frag[8 * 2 * 64 * 8]; // A of GEMM2 (E^T): x keyed by i, 16KB
    __shared__ unsigned short m_frag [4 * 4 * 64 * 8]; // B of GEMM1: m keyed by o, 16KB
    __shared__ unsigned short wT_frag[4 * 2 * 64 * 8]; // B of GEMM2: w keyed by o, 8KB
    __shared__ float xx2[256];
    __shared__ float xxc[TCHUNK];
    __shared__ float mm_s[NO];
    __shared__ float ss_s[NO];
    __shared__ float w1_s[NO];

    const int tid   = threadIdx.x;
    const int b     = blockIdx.x >> 5;       // / NCHUNK
    const int chunk = blockIdx.x & (NCHUNK - 1);
    const int t0    = chunk * TCHUNK;

    if (tid < NO) { mm_s[tid] = 0.f; w1_s[tid] = 0.f; ss_s[tid] = s[tid]; }
    __syncthreads();

    // ---- stage x chunk: 64 rows x 128 cols. thread = (t = tid>>2, quarter = tid&3)
    {
        const int t  = tid >> 2;
        const int q4 = tid & 3;
        const float* xg = x + ((size_t)b * T_DIM + t0 + t) * NI + q4 * 32;
        const int ttile = t >> 4, tm = t & 15;
        const int ksT = t >> 5, qT = (t & 31) >> 3, jT = t & 7; // xT coords for this t
        float sumsq = 0.f;
        #pragma unroll
        for (int f = 0; f < 8; ++f) {
            float4 v = reinterpret_cast<const float4*>(xg)[f];
            sumsq += v.x * v.x + v.y * v.y + v.z * v.z + v.w * v.w;
            const int i0 = q4 * 32 + f * 4;
            unsigned short h0 = f2bf(v.x), h1 = f2bf(v.y), h2 = f2bf(v.z), h3 = f2bf(v.w);
            // x_frag (A-frag of GEMM1): [ttile][ks=i>>5][slot=tm+16*((i&31)>>3)][j=i&7]
            {
                const int ks = i0 >> 5, q = (i0 & 31) >> 3, j0 = i0 & 7;
                const int base = (((ttile * 4 + ks) * 64) + tm + 16 * q) * 8 + j0;
                ushort4 hv; hv.x = h0; hv.y = h1; hv.z = h2; hv.w = h3;
                *reinterpret_cast<ushort4*>(&x_frag[base]) = hv;
            }
            // xT_frag (A-frag of GEMM2 keyed by i): [itile=i>>4][ks=t>>5][slot=(i&15)+16*qT][j=jT]
            {
                int i;
                i = i0 + 0; xT_frag[(((i >> 4) * 2 + ksT) * 64 + (i & 15) + 16 * qT) * 8 + jT] = h0;
                i = i0 + 1; xT_frag[(((i >> 4) * 2 + ksT) * 64 + (i & 15) + 16 * qT) * 8 + jT] = h1;
                i = i0 + 2; xT_frag[(((i >> 4) * 2 + ksT) * 64 + (i & 15) + 16 * qT) * 8 + jT] = h2;
                i = i0 + 3; xT_frag[(((i >> 4) * 2 + ksT) * 64 + (i & 15) + 16 * qT) * 8 + jT] = h3;
            }
        }
        xx2[tid] = sumsq;
    }

    // ---- stage m: thread = (o = tid&63, iblock = tid>>6). coalesced global reads.
    {
        const int o = tid & 63;
        const int ib = tid >> 6;             // kstep 0..3, i in [32*ib, 32*ib+32)
        const int otile = o >> 4, om = o & 15;
        float mml = 0.f;
        #pragma unroll
        for (int ii = 0; ii < 32; ++ii) {
            const int i = ib * 32 + ii;
            const float v = m[(size_t)i * NO + o];
            mml += v * v;
            const int q = ii >> 3, j = ii & 7;
            m_frag[(((otile * 4 + ib) * 64) + om + 16 * q) * 8 + j] = f2bf(v);
        }
        atomicAdd(&mm_s[o], mml);
    }
    __syncthreads();
    if (tid < TCHUNK)
        xxc[tid] = xx2[4 * tid] + xx2[4 * tid + 1] + xx2[4 * tid + 2] + xx2[4 * tid + 3];
    __syncthreads();

    const int wv   = tid >> 6;   // wave id
    const int lane = tid & 63;
    const int quad = lane >> 4, c = lane & 15;

    // ---- GEMM1: S[t][o] = sum_i x[t][i]*m[i][o].  M=t(16/wave), N=o(64), K=128.
    floatx4 zero = {0.f, 0.f, 0.f, 0.f};
    floatx4 acc[4];
    #pragma unroll
    for (int ot = 0; ot < 4; ++ot) acc[ot] = zero;
    #pragma unroll
    for (int ks = 0; ks < 4; ++ks) {
        short8 a = *reinterpret_cast<const short8*>(&x_frag[((wv * 4 + ks) * 64 + lane) * 8]);
        #pragma unroll
        for (int ot = 0; ot < 4; ++ot) {
            short8 bb = *reinterpret_cast<const short8*>(&m_frag[((ot * 4 + ks) * 64 + lane) * 8]);
            acc[ot] = __builtin_amdgcn_mfma_f32_16x16x32_bf16(a, bb, acc[ot], 0, 0, 0);
        }
    }

    // ---- d = s_o*(xx_t - 2 dot + mm_o); softmax over o (regs + shfl within 16-lane group)
    float sv[4], mv[4];
    #pragma unroll
    for (int ot = 0; ot < 4; ++ot) { sv[ot] = ss_s[16 * ot + c]; mv[ot] = mm_s[16 * ot + c]; }
    floatx4 xxq = *reinterpret_cast<const floatx4*>(&xxc[wv * 16 + quad * 4]);

    float w[4][4];
    #pragma unroll
    for (int r = 0; r < 4; ++r) {
        float mx = -1e30f;
        #pragma unroll
        for (int ot = 0; ot < 4; ++ot) {
            float d = sv[ot] * (xxq[r] - 2.f * acc[ot][r] + mv[ot]);
            w[ot][r] = d;
            mx = fmaxf(mx, d);
        }
        #pragma unroll
        for (int off = 1; off < 16; off <<= 1) mx = fmaxf(mx, __shfl_xor(mx, off, 64));
        float sum = 0.f;
        #pragma unroll
        for (int ot = 0; ot < 4; ++ot) { float e = __expf(w[ot][r] - mx); w[ot][r] = e; sum += e; }
        #pragma unroll
        for (int off = 1; off < 16; off <<= 1) sum += __shfl_xor(sum, off, 64);
        const float inv = 1.f / sum;
        #pragma unroll
        for (int ot = 0; ot < 4; ++ot) w[ot][r] *= inv;
    }

    // ---- W1[o] += sum_t w
    #pragma unroll
    for (int ot = 0; ot < 4; ++ot) {
        float lsum = w[ot][0] + w[ot][1] + w[ot][2] + w[ot][3];
        lsum += __shfl_xor(lsum, 16, 64);
        lsum += __shfl_xor(lsum, 32, 64);
        if (quad == 0) atomicAdd(&w1_s[16 * ot + c], lsum);
    }

    // ---- write w to wT_frag (B-frag of GEMM2: B[k=t][n=o])
    #pragma unroll
    for (int ot = 0; ot < 4; ++ot)
        #pragma unroll
        for (int r = 0; r < 4; ++r) {
            const int t  = wv * 16 + quad * 4 + r;
            const int ks = t >> 5, qd = (t & 31) >> 3, j = t & 7;
            wT_frag[((ot * 2 + ks) * 64 + c + 16 * qd) * 8 + j] = f2bf(w[ot][r]);
        }
    __syncthreads();

    // ---- GEMM2 (E^T): Et[i][o] = sum_t x[t][i]*w[t][o]. M=i(2 tiles/wave), N=o(64), K=64.
    // C/D layout: row = i = quad*4 + reg (4 CONSECUTIVE i per lane), col = o = lane&15.
    floatx4 acc2[2][4];
    #pragma unroll
    for (int it2 = 0; it2 < 2; ++it2)
        #pragma unroll
        for (int ot = 0; ot < 4; ++ot) acc2[it2][ot] = zero;
    #pragma unroll
    for (int ks = 0; ks < 2; ++ks) {
        short8 a0 = *reinterpret_cast<const short8*>(&xT_frag[(((2 * wv + 0) * 2 + ks) * 64 + lane) * 8]);
        short8 a1 = *reinterpret_cast<const short8*>(&xT_frag[(((2 * wv + 1) * 2 + ks) * 64 + lane) * 8]);
        #pragma unroll
        for (int ot = 0; ot < 4; ++ot) {
            short8 bb = *reinterpret_cast<const short8*>(&wT_frag[((ot * 2 + ks) * 64 + lane) * 8]);
            acc2[0][ot] = __builtin_amdgcn_mfma_f32_16x16x32_bf16(a0, bb, acc2[0][ot], 0, 0, 0);
            acc2[1][ot] = __builtin_amdgcn_mfma_f32_16x16x32_bf16(a1, bb, acc2[1][ot], 0, 0, 0);
        }
    }

    // ---- store bf16 partials, lane-sequential: slot = (it2*4+ot)*256 + tid, 4 shorts each.
    // Mapping: value r of slot -> o = ot*16 + (tid&15), i = (2*(tid>>6)+it2)*16 + ((tid>>4)&3)*4 + r
    unsigned short* pe = part_e + (size_t)blockIdx.x * (NO * NI);
    #pragma unroll
    for (int it2 = 0; it2 < 2; ++it2)
        #pragma unroll
        for (int ot = 0; ot < 4; ++ot) {
            ushort4 h;
            h.x = f2bf(acc2[it2][ot][0]); h.y = f2bf(acc2[it2][ot][1]);
            h.z = f2bf(acc2[it2][ot][2]); h.w = f2bf(acc2[it2][ot][3]);
            *reinterpret_cast<ushort4*>(&pe[(((it2 * 4 + ot) * 256) + tid) * 4]) = h;
        }
    if (tid < NO) part_w1[blockIdx.x * NO + tid] = w1_s[tid];
}

// Reduce: 512 blocks x 64 threads; each lane owns one float4 of out.
// Reads partials in the exact lane-sequential order they were stored (512B/instr contiguous).
__global__ __launch_bounds__(64) void lde_reduce(
    const unsigned short* __restrict__ part_e,  // (B*NCHUNK, 8192)
    const float* __restrict__ part_w1,          // (B*NCHUNK, NO)
    const float* __restrict__ m,                // (NI,NO)
    float* __restrict__ out)                    // (B,NO,NI)
{
    const int tid = threadIdx.x;                 // 0..63
    const int blk = blockIdx.x;                  // 0..511
    const int b      = blk >> 5;
    const int within = ((blk & 31) << 6) + tid;  // 0..2047, slot*4 shorts into each chunk's partial
    const int k    = (blk >> 2) & 7;             // = it2*4 + ot (block-uniform)
    const int ot   = k & 3, it2 = k >> 2;
    const int wv   = blk & 3;
    const int quad = tid >> 4;
    const int c    = tid & 15;
    const int o    = ot * 16 + c;
    const int i0   = (2 * wv + it2) * 16 + quad * 4;

    // w1[b,o]: each lane sums 8 chunks for its o, then butterfly over quad (lane bits 4,5)
    float w1v = 0.f;
    const float* pw = part_w1 + (size_t)b * NCHUNK * NO + o;
    #pragma unroll
    for (int j = 0; j < 8; ++j) w1v += pw[(quad * 8 + j) * NO];
    w1v += __shfl_xor(w1v, 16, 64);
    w1v += __shfl_xor(w1v, 32, 64);

    // sum bf16 partials over 32 chunks (fp32 accumulate)
    float a0 = 0.f, a1 = 0.f, a2 = 0.f, a3 = 0.f;
    const unsigned short* pp = part_e + (size_t)b * NCHUNK * (NO * NI) + (size_t)within * 4;
    #pragma unroll
    for (int cc = 0; cc < NCHUNK; ++cc) {
        ushort4 v = *reinterpret_cast<const ushort4*>(pp + (size_t)cc * (NO * NI));
        a0 += bf2f(v.x); a1 += bf2f(v.y); a2 += bf2f(v.z); a3 += bf2f(v.w);
    }

    const float inv = 1.f / (float)T_DIM;
    float4 r;
    r.x = (a0 - w1v * m[(i0 + 0) * NO + o]) * inv;
    r.y = (a1 - w1v * m[(i0 + 1) * NO + o]) * inv;
    r.z = (a2 - w1v * m[(i0 + 2) * NO + o]) * inv;
    r.w = (a3 - w1v * m[(i0 + 3) * NO + o]) * inv;
    *reinterpret_cast<float4*>(&out[((size_t)b * NO + o) * NI + i0]) = r;
}

extern "C" void kernel_launch(void* const* d_in, const int* in_sizes, int n_in,
                              void* d_out, int out_size, void* d_ws, size_t ws_size,
                              hipStream_t stream) {
    const float* x = (const float*)d_in[0];
    const float* s = (const float*)d_in[1];
    const float* m = (const float*)d_in[2];
    float* out = (float*)d_out;                                   // B*NO*NI floats
    unsigned short* part_e = (unsigned short*)d_ws;               // 512*8192 bf16 = 8.4 MB
    float* part_w1 = (float*)(part_e + (size_t)B_DIM * NCHUNK * NO * NI);  // 512*64 floats

    lde_main<<<dim3(B_DIM * NCHUNK), dim3(256), 0, stream>>>(x, s, m, part_e, part_w1);
    lde_reduce<<<dim3(B_DIM * NCHUNK), dim3(64), 0, stream>>>(part_e, part_w1, m, out);
}